// Round 1
// baseline (707.814 us; speedup 1.0000x reference)
//
#include <hip/hip_runtime.h>

// VariationalMPS: <M|H|M> / <M|M> via split-half environment sweeps.
// Left env L[a][w][b] (bra-bond, MPO-bond, ket-bond), right env in same layout
// via bond-transposed tensors. 20 sequential steps, 2 kernels per step.

#define D 128
#define W 8
#define NS 40
#define HALF 20
#define MSZ (D * 2 * D)     // 32768 floats per site M
#define HSZ (W * W * 2 * 2) // 256 floats per site H
#define LSZ (D * W * D)     // 131072
#define NSZ (D * D)         // 16384
#define T2SZ (D * W * D * 2) // 262144
#define TNSZ (D * 2 * D)     // 32768

// workspace float offsets
#define OFF_LL 0
#define OFF_LR (OFF_LL + LSZ)   // 131072
#define OFF_NL (OFF_LR + LSZ)   // 262144
#define OFF_NR (OFF_NL + NSZ)   // 278528
#define OFF_T2L (OFF_NR + NSZ)  // 294912
#define OFF_T2R (OFF_T2L + T2SZ)
#define OFF_TNL (OFF_T2R + T2SZ)
#define OFF_TNR (OFF_TNL + TNSZ)
#define OFF_MREV (OFF_TNR + TNSZ)
#define OFF_HREV (OFF_MREV + HALF * MSZ)
#define WS_FLOATS (OFF_HREV + HALF * HSZ) // 1,545,216 floats = 6.18 MB

// Zero the four environment buffers and set boundary ones.
__global__ __launch_bounds__(256) void k_init(float* ws) {
    int idx = blockIdx.x * 256 + threadIdx.x;
    if (idx < OFF_T2L) {
        float v = 0.f;
        if (idx == 0) v = 1.f;                        // L_left[0,0,0]
        else if (idx == OFF_LR + (W - 1) * D) v = 1.f; // L_right[0,W-1,0]
        else if (idx == OFF_NL) v = 1.f;              // N_left[0,0]
        else if (idx == OFF_NR) v = 1.f;              // N_right[0,0]
        ws[idx] = v;
    }
}

// Build reversed/transposed tensors for the right sweep:
// Mrev[k][p][i][a] = M[39-k][a][i][p];  Hrev[k][x][w][i][j] = H[39-k][w][x][i][j]
__global__ __launch_bounds__(256) void k_prep(const float* __restrict__ Min,
                                              const float* __restrict__ Hin,
                                              float* __restrict__ ws) {
    int idx = blockIdx.x * 256 + threadIdx.x;
    if (idx < HALF * MSZ) {
        int k = idx >> 15;
        int r = idx & (MSZ - 1);
        int p = r >> 8;
        int i = (r >> 7) & 1;
        int a = r & 127;
        ws[OFF_MREV + idx] = Min[(NS - 1 - k) * MSZ + a * 256 + i * 128 + p];
    } else {
        int idx2 = idx - HALF * MSZ;
        if (idx2 < HALF * HSZ) {
            int k = idx2 >> 8;
            int r = idx2 & 255;
            int x = r >> 5, w = (r >> 2) & 7, i = (r >> 1) & 1, j = r & 1;
            ws[OFF_HREV + idx2] = Hin[(NS - 1 - k) * HSZ + w * 32 + x * 4 + i * 2 + j];
        }
    }
}

// KA: energy phases 1+2 (blocks 0..511, 256 per side) and norm phase A
// (blocks 512..575, 32 per side).
// Energy: T1[w,b,i,p] = sum_a L[a,w,b] m[a,i,p]  (block tile: all w,i; 8 b x 8 p)
//         T2[b,p,x,j] = sum_{w,i} T1[w,b,i,p] h[w,x,i,j], stored [p][x][b][j]
// Norm:   Tn(b,i,p) = sum_a N[a,b] m[a,i,p], stored [p][b*2+i]
__global__ __launch_bounds__(256) void k_A(const float* __restrict__ Min,
                                           const float* __restrict__ Hin,
                                           float* __restrict__ ws, int k) {
    __shared__ float sm[4096];
    int bid = blockIdx.x;
    int t = threadIdx.x;
    if (bid < 512) {
        int side = bid >> 8;
        int eb = bid & 255;
        int b0 = (eb & 15) * 8;
        int p0 = (eb >> 4) * 8;
        const float* Lsrc = ws + (side ? OFF_LR : OFF_LL);
        const float* m = side ? (ws + OFF_MREV + k * MSZ) : (Min + k * MSZ);
        const float* h = side ? (ws + OFF_HREV + k * HSZ) : (Hin + k * HSZ);
        float* T2 = ws + (side ? OFF_T2R : OFF_T2L);
        float* Ls = sm;         // [32][65]
        float* ms = sm + 2080;  // [32][17]
        float* hs = sm + 2624;  // [16][16]  hs[wi][xj]
        float* T1s = sm + 2880; // [64][17]
        {
            int wi = t >> 4, xj = t & 15;
            hs[t] = h[(wi >> 1) * 32 + (xj >> 1) * 4 + (wi & 1) * 2 + (xj & 1)];
        }
        int pair = t >> 2, s = t & 3;
        int bl = pair >> 3, pl = pair & 7;
        float acc0 = 0, acc1 = 0, acc2 = 0, acc3 = 0;
        for (int c = 0; c < 4; ++c) {
            int a0 = c * 32;
            __syncthreads();
            for (int u = 0; u < 8; ++u) {
                int e = u * 256 + t;
                int kk = e >> 6, col = e & 63;
                Ls[kk * 65 + col] =
                    Lsrc[(a0 + kk) * 1024 + (col >> 3) * 128 + b0 + (col & 7)];
            }
            for (int u = 0; u < 2; ++u) {
                int e = u * 256 + t;
                int kk = e >> 4, col = e & 15;
                ms[kk * 17 + col] =
                    m[(a0 + kk) * 256 + (col >> 3) * 128 + p0 + (col & 7)];
            }
            __syncthreads();
            int w0 = 2 * s;
            for (int kk = 0; kk < 32; ++kk) {
                float lv0 = Ls[kk * 65 + w0 * 8 + bl];
                float lv1 = Ls[kk * 65 + (w0 + 1) * 8 + bl];
                float mv0 = ms[kk * 17 + pl];
                float mv1 = ms[kk * 17 + 8 + pl];
                acc0 += lv0 * mv0;
                acc1 += lv0 * mv1;
                acc2 += lv1 * mv0;
                acc3 += lv1 * mv1;
            }
        }
        // acc[v] = T1[w=2s+(v>>1), b0+bl, i=v&1, p0+pl] -> T1s[pair][wi=4s+v]
        T1s[pair * 17 + 4 * s + 0] = acc0;
        T1s[pair * 17 + 4 * s + 1] = acc1;
        T1s[pair * 17 + 4 * s + 2] = acc2;
        T1s[pair * 17 + 4 * s + 3] = acc3;
        __syncthreads();
        float o0 = 0, o1 = 0, o2 = 0, o3 = 0;
        for (int wi = 0; wi < 16; ++wi) {
            float tv = T1s[pair * 17 + wi];
            o0 += tv * hs[wi * 16 + s];
            o1 += tv * hs[wi * 16 + s + 4];
            o2 += tv * hs[wi * 16 + s + 8];
            o3 += tv * hs[wi * 16 + s + 12];
        }
        int b = b0 + bl, p = p0 + pl;
        int base = p * 2048 + b * 2; // T2[p][x][b][j]: p:2048, x:256, b:2, j:1
        int xj;
        xj = s;      T2[base + (xj >> 1) * 256 + (xj & 1)] = o0;
        xj = s + 4;  T2[base + (xj >> 1) * 256 + (xj & 1)] = o1;
        xj = s + 8;  T2[base + (xj >> 1) * 256 + (xj & 1)] = o2;
        xj = s + 12; T2[base + (xj >> 1) * 256 + (xj & 1)] = o3;
    } else {
        int nb = bid - 512;
        int side = nb >> 5;
        int nn = nb & 31;
        int b0 = (nn & 3) * 32;
        int c0 = (nn >> 2) * 32;
        const float* Nsrc = ws + (side ? OFF_NR : OFF_NL);
        const float* m = side ? (ws + OFF_MREV + k * MSZ) : (Min + k * MSZ);
        float* Tn = ws + (side ? OFF_TNR : OFF_TNL);
        float* As = sm;         // [32][33]
        float* Bs = sm + 1056;  // [32][33]
        int ty = t >> 4, tx = t & 15;
        float a00 = 0, a01 = 0, a10 = 0, a11 = 0;
        for (int c = 0; c < 4; ++c) {
            int a0 = c * 32;
            __syncthreads();
            for (int u = 0; u < 4; ++u) {
                int e = u * 256 + t;
                int kk = e >> 5, col = e & 31;
                As[kk * 33 + col] = Nsrc[(a0 + kk) * 128 + b0 + col];
                Bs[kk * 33 + col] = m[(a0 + kk) * 256 + c0 + col];
            }
            __syncthreads();
            for (int kk = 0; kk < 32; ++kk) {
                float av0 = As[kk * 33 + 2 * ty], av1 = As[kk * 33 + 2 * ty + 1];
                float bv0 = Bs[kk * 33 + 2 * tx], bv1 = Bs[kk * 33 + 2 * tx + 1];
                a00 += av0 * bv0;
                a01 += av0 * bv1;
                a10 += av1 * bv0;
                a11 += av1 * bv1;
            }
        }
        int b_ = b0 + 2 * ty;
        int ip0 = c0 + 2 * tx, ip1 = ip0 + 1;
        int p0_ = ip0 & 127, i0 = ip0 >> 7;
        int p1_ = ip1 & 127, i1 = ip1 >> 7;
        Tn[p0_ * 256 + b_ * 2 + i0] = a00;
        Tn[p1_ * 256 + b_ * 2 + i1] = a01;
        Tn[p0_ * 256 + (b_ + 1) * 2 + i0] = a10;
        Tn[p1_ * 256 + (b_ + 1) * 2 + i1] = a11;
    }
}

// KB: C[r][c] = sum_k A[r][k] * B[k][c], A row-major (K=256 contiguous),
// B = site m viewed as (256,128) K-major. Energy: M=1024 rows (p,x), C=L'.
// Norm: M=128 rows (p), C=N'. Blocks: 0..255 energy (128/side), 256..287 norm.
__global__ __launch_bounds__(256) void k_B(const float* __restrict__ Min,
                                           float* __restrict__ ws, int k) {
    __shared__ float sm[2112];
    int bid = blockIdx.x, t = threadIdx.x;
    const float* A;
    const float* B;
    float* C;
    int r0, c0;
    if (bid < 256) {
        int side = bid >> 7;
        int eb = bid & 127;
        r0 = (eb & 31) * 32;
        c0 = (eb >> 5) * 32;
        A = ws + (side ? OFF_T2R : OFF_T2L);
        B = side ? (ws + OFF_MREV + k * MSZ) : (Min + k * MSZ);
        C = ws + (side ? OFF_LR : OFF_LL);
    } else {
        int nb = bid - 256;
        int side = nb >> 4;
        int nn = nb & 15;
        r0 = (nn & 3) * 32;
        c0 = (nn >> 2) * 32;
        A = ws + (side ? OFF_TNR : OFF_TNL);
        B = side ? (ws + OFF_MREV + k * MSZ) : (Min + k * MSZ);
        C = ws + (side ? OFF_NR : OFF_NL);
    }
    float* As = sm;        // [32][33]
    float* Bs = sm + 1056; // [32][33]
    int ty = t >> 4, tx = t & 15;
    float a00 = 0, a01 = 0, a10 = 0, a11 = 0;
    for (int c = 0; c < 8; ++c) {
        int k0 = c * 32;
        __syncthreads();
        for (int u = 0; u < 4; ++u) {
            int e = u * 256 + t;
            int rr = e >> 5, kk = e & 31;
            As[kk * 33 + rr] = A[(r0 + rr) * 256 + k0 + kk];
        }
        for (int u = 0; u < 4; ++u) {
            int e = u * 256 + t;
            int kk = e >> 5, cc = e & 31;
            Bs[kk * 33 + cc] = B[(k0 + kk) * 128 + c0 + cc];
        }
        __syncthreads();
        for (int kk = 0; kk < 32; ++kk) {
            float av0 = As[kk * 33 + 2 * ty], av1 = As[kk * 33 + 2 * ty + 1];
            float bv0 = Bs[kk * 33 + 2 * tx], bv1 = Bs[kk * 33 + 2 * tx + 1];
            a00 += av0 * bv0;
            a01 += av0 * bv1;
            a10 += av1 * bv0;
            a11 += av1 * bv1;
        }
    }
    int r = r0 + 2 * ty, cc0 = c0 + 2 * tx;
    C[r * 128 + cc0] = a00;
    C[r * 128 + cc0 + 1] = a01;
    C[(r + 1) * 128 + cc0] = a10;
    C[(r + 1) * 128 + cc0 + 1] = a11;
}

// Final: energy = <L_left, L_right>, norm = <N_left, N_right>, then loss & reg.
__global__ __launch_bounds__(256) void k_final(const float* __restrict__ ws,
                                               float* __restrict__ out) {
    __shared__ float se[256], sn[256];
    int t = threadIdx.x;
    const float* LL = ws + OFF_LL;
    const float* LR = ws + OFF_LR;
    const float* NLp = ws + OFF_NL;
    const float* NRp = ws + OFF_NR;
    float e = 0, n = 0;
    for (int i = t; i < LSZ; i += 256) e += LL[i] * LR[i];
    for (int i = t; i < NSZ; i += 256) n += NLp[i] * NRp[i];
    se[t] = e;
    sn[t] = n;
    __syncthreads();
    for (int s = 128; s > 0; s >>= 1) {
        if (t < s) {
            se[t] += se[t + s];
            sn[t] += sn[t + s];
        }
        __syncthreads();
    }
    if (t == 0) {
        float E = se[0], Nm = sn[0];
        out[0] = E;
        out[1] = Nm;
        out[2] = E / Nm;
        out[3] = fmaxf(Nm - 10000.0f, 0.0f);
    }
}

extern "C" void kernel_launch(void* const* d_in, const int* in_sizes, int n_in,
                              void* d_out, int out_size, void* d_ws, size_t ws_size,
                              hipStream_t stream) {
    const float* Min = (const float*)d_in[0];
    const float* Hin = (const float*)d_in[1];
    float* ws = (float*)d_ws;
    float* out = (float*)d_out;
    (void)in_sizes; (void)n_in; (void)out_size; (void)ws_size;

    k_init<<<dim3((OFF_T2L + 255) / 256), dim3(256), 0, stream>>>(ws);
    k_prep<<<dim3((HALF * MSZ + HALF * HSZ + 255) / 256), dim3(256), 0, stream>>>(Min, Hin, ws);
    for (int k = 0; k < HALF; ++k) {
        k_A<<<dim3(576), dim3(256), 0, stream>>>(Min, Hin, ws, k);
        k_B<<<dim3(288), dim3(256), 0, stream>>>(Min, ws, k);
    }
    k_final<<<dim3(1), dim3(256), 0, stream>>>(ws, out);
}

// Round 2
// 493.993 us; speedup vs baseline: 1.4328x; 1.4328x over previous
//
#include <hip/hip_runtime.h>

// VariationalMPS: <M|H|M> / <M|M> via split-half environment sweeps.
// Left env L[a][w][b], right env via bond-transposed tensors. 20 steps x 2 kernels.
// R2: fused-register phase-2 in k_A (16x16 tile), 2x4 microtile k_B, multi-block dot.

#define D 128
#define W 8
#define NS 40
#define HALF 20
#define MSZ (D * 2 * D)      // 32768
#define HSZ (W * W * 2 * 2)  // 256
#define LSZ (D * W * D)      // 131072
#define NSZ (D * D)          // 16384
#define T2SZ (D * W * D * 2) // 262144
#define TNSZ (D * 2 * D)     // 32768

#define OFF_LL 0
#define OFF_LR (OFF_LL + LSZ)
#define OFF_NL (OFF_LR + LSZ)
#define OFF_NR (OFF_NL + NSZ)
#define OFF_T2L (OFF_NR + NSZ)  // 294912 — envs live below this
#define OFF_T2R (OFF_T2L + T2SZ)
#define OFF_TNL (OFF_T2R + T2SZ)
#define OFF_TNR (OFF_TNL + TNSZ)
#define OFF_MREV (OFF_TNR + TNSZ)
#define OFF_HREV (OFF_MREV + HALF * MSZ)
#define OFF_PART (OFF_HREV + HALF * HSZ)   // 128 energy partials
#define OFF_PARTN (OFF_PART + 128)         // 128 norm partials
#define WS_FLOATS (OFF_PARTN + 128)

__global__ __launch_bounds__(256) void k_init(float* ws) {
    int idx = blockIdx.x * 256 + threadIdx.x;
    if (idx < OFF_T2L) {
        float v = 0.f;
        if (idx == 0) v = 1.f;                         // L_left[0,0,0]
        else if (idx == OFF_LR + (W - 1) * D) v = 1.f; // L_right[0,W-1,0]
        else if (idx == OFF_NL) v = 1.f;               // N_left[0,0]
        else if (idx == OFF_NR) v = 1.f;               // N_right[0,0]
        ws[idx] = v;
    }
}

// Mrev[k][p][i][a] = M[39-k][a][i][p];  Hrev[k][x][w][i][j] = H[39-k][w][x][i][j]
__global__ __launch_bounds__(256) void k_prep(const float* __restrict__ Min,
                                              const float* __restrict__ Hin,
                                              float* __restrict__ ws) {
    int idx = blockIdx.x * 256 + threadIdx.x;
    if (idx < HALF * MSZ) {
        int k = idx >> 15;
        int r = idx & (MSZ - 1);
        int p = r >> 8;
        int i = (r >> 7) & 1;
        int a = r & 127;
        ws[OFF_MREV + idx] = Min[(NS - 1 - k) * MSZ + a * 256 + i * 128 + p];
    } else {
        int idx2 = idx - HALF * MSZ;
        if (idx2 < HALF * HSZ) {
            int k = idx2 >> 8;
            int r = idx2 & 255;
            int x = r >> 5, w = (r >> 2) & 7, i = (r >> 1) & 1, j = r & 1;
            ws[OFF_HREV + idx2] = Hin[(NS - 1 - k) * HSZ + w * 32 + x * 4 + i * 2 + j];
        }
    }
}

// KA: energy blocks 0..127 (64/side): T1[w,b,i,p]=sum_a L[a,w,b] m[a,i,p] with
// 16b x 16p tile, all (w,i) per thread; phase 2 (h contraction) fused in regs;
// writes T2[p][x][b][j]. Norm blocks 128..191: Tn(b,i,p)=sum_a N[a,b] m[a,i,p].
__global__ __launch_bounds__(256) void k_A(const float* __restrict__ Min,
                                           const float* __restrict__ Hin,
                                           float* __restrict__ ws, int k) {
    __shared__ float sm[7680];
    int bid = blockIdx.x;
    int t = threadIdx.x;
    if (bid < 128) {
        int side = bid >> 6;
        int eb = bid & 63;
        int b0 = (eb & 7) * 16;
        int p0 = (eb >> 3) * 16;
        const float* Lsrc = ws + (side ? OFF_LR : OFF_LL);
        const float* m = side ? (ws + OFF_MREV + k * MSZ) : (Min + k * MSZ);
        const float* h = side ? (ws + OFF_HREV + k * HSZ) : (Hin + k * HSZ);
        float* T2 = ws + (side ? OFF_T2R : OFF_T2L);
        float* Ls = sm;          // [32a][16b][8w pad->12], row stride 200
        float* ms = sm + 6400;   // [32a][2i][16p]
        float* hs = sm + 7424;   // [16wi][16xj]
        hs[t] = h[((t >> 4) >> 1) * 32 + ((t & 15) >> 1) * 4 + ((t >> 4) & 1) * 2 + (t & 1)];
        int b_l = t & 15, p_l = t >> 4;
        float acc[8][2];
#pragma unroll
        for (int w = 0; w < 8; ++w) { acc[w][0] = 0.f; acc[w][1] = 0.f; }
        for (int c = 0; c < 4; ++c) {
            int a0 = c * 32;
            __syncthreads();
            // stage L: 32a x 8w x 16b, float4 along b, scatter stride-12 writes
#pragma unroll
            for (int u = 0; u < 4; ++u) {
                int e = u * 256 + t;
                int aa = e >> 5, w = (e >> 2) & 7, bq = e & 3;
                const float4 v = *(const float4*)&Lsrc[(a0 + aa) * 1024 + w * 128 + b0 + bq * 4];
                float* dst = &Ls[aa * 200 + bq * 48 + w];
                dst[0] = v.x; dst[12] = v.y; dst[24] = v.z; dst[36] = v.w;
            }
            // stage m: 32a x 2i x 16p, float4 along p
            {
                int aa = t >> 3, i = (t >> 2) & 1, pq = t & 3;
                const float4 v = *(const float4*)&m[(a0 + aa) * 256 + i * 128 + p0 + pq * 4];
                *(float4*)&ms[aa * 32 + i * 16 + pq * 4] = v;
            }
            __syncthreads();
#pragma unroll 4
            for (int aa = 0; aa < 32; ++aa) {
                float4 l0 = *(float4*)&Ls[aa * 200 + b_l * 12];
                float4 l1 = *(float4*)&Ls[aa * 200 + b_l * 12 + 4];
                float m0 = ms[aa * 32 + p_l];
                float m1 = ms[aa * 32 + 16 + p_l];
                acc[0][0] += l0.x * m0; acc[0][1] += l0.x * m1;
                acc[1][0] += l0.y * m0; acc[1][1] += l0.y * m1;
                acc[2][0] += l0.z * m0; acc[2][1] += l0.z * m1;
                acc[3][0] += l0.w * m0; acc[3][1] += l0.w * m1;
                acc[4][0] += l1.x * m0; acc[4][1] += l1.x * m1;
                acc[5][0] += l1.y * m0; acc[5][1] += l1.y * m1;
                acc[6][0] += l1.z * m0; acc[6][1] += l1.z * m1;
                acc[7][0] += l1.w * m0; acc[7][1] += l1.w * m1;
            }
        }
        // phase 2 in registers: o[x*2+j] = sum_wi T1[wi] * hs[wi][xj]
        float o[16];
#pragma unroll
        for (int xj = 0; xj < 16; ++xj) o[xj] = 0.f;
#pragma unroll
        for (int wi = 0; wi < 16; ++wi) {
            float tv = acc[wi >> 1][wi & 1];
            float4 h0 = *(float4*)&hs[wi * 16];
            float4 h1 = *(float4*)&hs[wi * 16 + 4];
            float4 h2 = *(float4*)&hs[wi * 16 + 8];
            float4 h3 = *(float4*)&hs[wi * 16 + 12];
            o[0] += tv * h0.x;  o[1] += tv * h0.y;  o[2] += tv * h0.z;  o[3] += tv * h0.w;
            o[4] += tv * h1.x;  o[5] += tv * h1.y;  o[6] += tv * h1.z;  o[7] += tv * h1.w;
            o[8] += tv * h2.x;  o[9] += tv * h2.y;  o[10] += tv * h2.z; o[11] += tv * h2.w;
            o[12] += tv * h3.x; o[13] += tv * h3.y; o[14] += tv * h3.z; o[15] += tv * h3.w;
        }
        int b = b0 + b_l, p = p0 + p_l;
        int base = p * 2048 + b * 2; // T2[p][x][b][j]
#pragma unroll
        for (int x = 0; x < 8; ++x) {
            float2 v; v.x = o[x * 2]; v.y = o[x * 2 + 1];
            *(float2*)&T2[base + x * 256] = v;
        }
    } else {
        int nb = bid - 128;
        int side = nb >> 5;
        int nn = nb & 31;
        int b0 = (nn & 3) * 32;
        int c0 = (nn >> 2) * 32;
        const float* Nsrc = ws + (side ? OFF_NR : OFF_NL);
        const float* m = side ? (ws + OFF_MREV + k * MSZ) : (Min + k * MSZ);
        float* Tn = ws + (side ? OFF_TNR : OFF_TNL);
        float* As = sm;         // [32][33]
        float* Bs = sm + 1056;  // [32][33]
        int ty = t >> 4, tx = t & 15;
        float a00 = 0, a01 = 0, a10 = 0, a11 = 0;
        for (int c = 0; c < 4; ++c) {
            int a0 = c * 32;
            __syncthreads();
            for (int u = 0; u < 4; ++u) {
                int e = u * 256 + t;
                int kk = e >> 5, col = e & 31;
                As[kk * 33 + col] = Nsrc[(a0 + kk) * 128 + b0 + col];
                Bs[kk * 33 + col] = m[(a0 + kk) * 256 + c0 + col];
            }
            __syncthreads();
            for (int kk = 0; kk < 32; ++kk) {
                float av0 = As[kk * 33 + 2 * ty], av1 = As[kk * 33 + 2 * ty + 1];
                float bv0 = Bs[kk * 33 + 2 * tx], bv1 = Bs[kk * 33 + 2 * tx + 1];
                a00 += av0 * bv0;
                a01 += av0 * bv1;
                a10 += av1 * bv0;
                a11 += av1 * bv1;
            }
        }
        int b_ = b0 + 2 * ty;
        int ip0 = c0 + 2 * tx, ip1 = ip0 + 1;
        int p0_ = ip0 & 127, i0 = ip0 >> 7;
        int p1_ = ip1 & 127, i1 = ip1 >> 7;
        Tn[p0_ * 256 + b_ * 2 + i0] = a00;
        Tn[p1_ * 256 + b_ * 2 + i1] = a01;
        Tn[p0_ * 256 + (b_ + 1) * 2 + i0] = a10;
        Tn[p1_ * 256 + (b_ + 1) * 2 + i1] = a11;
    }
}

// KB: C[r][c] = sum_k A[r][k] B[k][c]; 32x64 tile, 2x4 microtile.
// Energy blocks 0..127 (64/side): A=T2 (1024x256), B=m (256x128), C=L'.
// Norm blocks 128..143 (8/side): A=Tn (128x256), C=N'.
__global__ __launch_bounds__(256) void k_B(const float* __restrict__ Min,
                                           float* __restrict__ ws, int k) {
    __shared__ float As[32 * 34];
    __shared__ float Bs[32 * 68];
    int bid = blockIdx.x, t = threadIdx.x;
    const float* A;
    const float* B;
    float* C;
    int r0, c0;
    if (bid < 128) {
        int side = bid >> 6;
        int eb = bid & 63;
        r0 = (eb & 31) * 32;
        c0 = (eb >> 5) * 64;
        A = ws + (side ? OFF_T2R : OFF_T2L);
        B = side ? (ws + OFF_MREV + k * MSZ) : (Min + k * MSZ);
        C = ws + (side ? OFF_LR : OFF_LL);
    } else {
        int nb = bid - 128;
        int side = nb >> 3;
        int nn = nb & 7;
        r0 = (nn & 3) * 32;
        c0 = (nn >> 2) * 64;
        A = ws + (side ? OFF_TNR : OFF_TNL);
        B = side ? (ws + OFF_MREV + k * MSZ) : (Min + k * MSZ);
        C = ws + (side ? OFF_NR : OFF_NL);
    }
    int ty = t >> 4, tx = t & 15;
    float a00 = 0, a01 = 0, a02 = 0, a03 = 0;
    float a10 = 0, a11 = 0, a12 = 0, a13 = 0;
    for (int c = 0; c < 8; ++c) {
        int k0 = c * 32;
        __syncthreads();
        { // stage A: 32r x 32k, float4 along k, scatter into As[kk][rr] (stride 34)
            int rr = t >> 3, kq = t & 7;
            const float4 v = *(const float4*)&A[(r0 + rr) * 256 + k0 + kq * 4];
            float* dst = &As[kq * 136 + rr];
            dst[0] = v.x; dst[34] = v.y; dst[68] = v.z; dst[102] = v.w;
        }
#pragma unroll
        for (int u = 0; u < 2; ++u) { // stage B: 32k x 64c, float4 along c
            int e = u * 256 + t;
            int kk = e >> 4, cq = e & 15;
            const float4 v = *(const float4*)&B[(k0 + kk) * 128 + c0 + cq * 4];
            *(float4*)&Bs[kk * 68 + cq * 4] = v;
        }
        __syncthreads();
#pragma unroll 8
        for (int kk = 0; kk < 32; ++kk) {
            float2 av = *(float2*)&As[kk * 34 + 2 * ty];
            float4 bv = *(float4*)&Bs[kk * 68 + 4 * tx];
            a00 += av.x * bv.x; a01 += av.x * bv.y; a02 += av.x * bv.z; a03 += av.x * bv.w;
            a10 += av.y * bv.x; a11 += av.y * bv.y; a12 += av.y * bv.z; a13 += av.y * bv.w;
        }
    }
    int r = r0 + 2 * ty, cc = c0 + 4 * tx;
    float4 v0; v0.x = a00; v0.y = a01; v0.z = a02; v0.w = a03;
    float4 v1; v1.x = a10; v1.y = a11; v1.z = a12; v1.w = a13;
    *(float4*)&C[r * 128 + cc] = v0;
    *(float4*)&C[(r + 1) * 128 + cc] = v1;
}

// Partial dots: 128 blocks; block b covers 1024 energy elems + 128 norm elems.
__global__ __launch_bounds__(256) void k_dot(float* __restrict__ ws) {
    __shared__ float se[256], sn[256];
    int bid = blockIdx.x, t = threadIdx.x;
    const float* LL = ws + OFF_LL;
    const float* LR = ws + OFF_LR;
    float e = 0.f;
#pragma unroll
    for (int u = 0; u < 4; ++u) {
        int i = bid * 1024 + u * 256 + t;
        e += LL[i] * LR[i];
    }
    float n = 0.f;
    if (t < 128) {
        int i = bid * 128 + t;
        n = ws[OFF_NL + i] * ws[OFF_NR + i];
    }
    se[t] = e;
    sn[t] = n;
    __syncthreads();
    for (int s = 128; s > 0; s >>= 1) {
        if (t < s) { se[t] += se[t + s]; sn[t] += sn[t + s]; }
        __syncthreads();
    }
    if (t == 0) {
        ws[OFF_PART + bid] = se[0];
        ws[OFF_PARTN + bid] = sn[0];
    }
}

__global__ __launch_bounds__(256) void k_loss(const float* __restrict__ ws,
                                              float* __restrict__ out) {
    __shared__ float se[128], sn[128];
    int t = threadIdx.x;
    if (t < 128) {
        se[t] = ws[OFF_PART + t];
        sn[t] = ws[OFF_PARTN + t];
    }
    __syncthreads();
    for (int s = 64; s > 0; s >>= 1) {
        if (t < s) { se[t] += se[t + s]; sn[t] += sn[t + s]; }
        __syncthreads();
    }
    if (t == 0) {
        float E = se[0], Nm = sn[0];
        out[0] = E;
        out[1] = Nm;
        out[2] = E / Nm;
        out[3] = fmaxf(Nm - 10000.0f, 0.0f);
    }
}

extern "C" void kernel_launch(void* const* d_in, const int* in_sizes, int n_in,
                              void* d_out, int out_size, void* d_ws, size_t ws_size,
                              hipStream_t stream) {
    const float* Min = (const float*)d_in[0];
    const float* Hin = (const float*)d_in[1];
    float* ws = (float*)d_ws;
    float* out = (float*)d_out;
    (void)in_sizes; (void)n_in; (void)out_size; (void)ws_size;

    k_init<<<dim3((OFF_T2L + 255) / 256), dim3(256), 0, stream>>>(ws);
    k_prep<<<dim3((HALF * MSZ + HALF * HSZ + 255) / 256), dim3(256), 0, stream>>>(Min, Hin, ws);
    for (int k = 0; k < HALF; ++k) {
        k_A<<<dim3(192), dim3(256), 0, stream>>>(Min, Hin, ws, k);
        k_B<<<dim3(144), dim3(256), 0, stream>>>(Min, ws, k);
    }
    k_dot<<<dim3(128), dim3(256), 0, stream>>>(ws);
    k_loss<<<dim3(1), dim3(256), 0, stream>>>(ws, out);
}